// Round 1
// baseline (133.040 us; speedup 1.0000x reference)
//
#include <hip/hip_runtime.h>
#include <cmath>

#define VOCAB   50257
#define HIDDEN  16
#define BATCH   256
#define SEQLEN  8192
#define TCHUNKS 4          // T split for K2 parallelism; partials summed in K3
#define K3_BCHUNK 64       // batch rows per K3 block

// ---------------------------------------------------------------------------
// K1: per-vocab fused table  c[v][k] = sigmoid(Wg.e+bg) * tanh((Wu^T e)[k]+bu[k])
// One thread per vocab row. Wu/Wg/bu staged in LDS (broadcast reads are free).
// ---------------------------------------------------------------------------
__global__ __launch_bounds__(256) void k1_build_table(
    const float* __restrict__ embed, const float* __restrict__ Wg,
    const float* __restrict__ bg,    const float* __restrict__ Wu,
    const float* __restrict__ bu,    float* __restrict__ ctab)
{
    __shared__ float sWu[256], sWg[16], sbu[16];
    const int tid = threadIdx.x;
    sWu[tid] = Wu[tid];
    if (tid < 16) { sWg[tid] = Wg[tid]; sbu[tid] = bu[tid]; }
    __syncthreads();

    const int v = blockIdx.x * 256 + tid;
    if (v >= VOCAB) return;

    const float4* er = (const float4*)(embed + (size_t)v * HIDDEN);
    float4 e0 = er[0], e1 = er[1], e2 = er[2], e3 = er[3];
    float e[16] = {e0.x,e0.y,e0.z,e0.w, e1.x,e1.y,e1.z,e1.w,
                   e2.x,e2.y,e2.z,e2.w, e3.x,e3.y,e3.z,e3.w};

    float z = bg[0];
#pragma unroll
    for (int h = 0; h < 16; ++h) z = fmaf(e[h], sWg[h], z);
    const float g = 1.0f / (1.0f + __expf(-z));

    float o[16];
#pragma unroll
    for (int k = 0; k < 16; ++k) {
        float u = sbu[k];
#pragma unroll
        for (int h = 0; h < 16; ++h) u = fmaf(e[h], sWu[h * 16 + k], u);
        o[k] = g * tanhf(u);
    }

    float4* cr = (float4*)(ctab + (size_t)v * HIDDEN);
    cr[0] = make_float4(o[0],  o[1],  o[2],  o[3]);
    cr[1] = make_float4(o[4],  o[5],  o[6],  o[7]);
    cr[2] = make_float4(o[8],  o[9],  o[10], o[11]);
    cr[3] = make_float4(o[12], o[13], o[14], o[15]);
}

// ---------------------------------------------------------------------------
// K2: memory[b] = sum_t c[seq[b,t]] — gather-sum over L2-resident 3.2 MB table.
// grid (BATCH, TCHUNKS), 256 threads. Wave shuffle-reduce 16 floats, then
// cross-wave LDS reduce; chunk partial written to ws (no atomics needed).
// ---------------------------------------------------------------------------
__global__ __launch_bounds__(256) void k2_accum(
    const int* __restrict__ seq, const float* __restrict__ ctab,
    float* __restrict__ partial)
{
    const int b = blockIdx.x, chunk = blockIdx.y, tid = threadIdx.x;
    const int TPC = SEQLEN / TCHUNKS;                     // 2048 tokens/chunk
    const int* srow = seq + (size_t)b * SEQLEN + chunk * TPC;

    float r[16];
#pragma unroll
    for (int k = 0; k < 16; ++k) r[k] = 0.f;

#pragma unroll
    for (int i = 0; i < TPC / 256; ++i) {                 // 8 tokens/thread
        const int idx = srow[i * 256 + tid];              // coalesced
        const float4* cr = (const float4*)(ctab + (size_t)idx * HIDDEN);
        float4 c0 = cr[0], c1 = cr[1], c2 = cr[2], c3 = cr[3];
        r[0]+=c0.x;  r[1]+=c0.y;  r[2]+=c0.z;  r[3]+=c0.w;
        r[4]+=c1.x;  r[5]+=c1.y;  r[6]+=c1.z;  r[7]+=c1.w;
        r[8]+=c2.x;  r[9]+=c2.y;  r[10]+=c2.z; r[11]+=c2.w;
        r[12]+=c3.x; r[13]+=c3.y; r[14]+=c3.z; r[15]+=c3.w;
    }

    // butterfly reduce across the 64-lane wave
#pragma unroll
    for (int off = 32; off > 0; off >>= 1)
#pragma unroll
        for (int k = 0; k < 16; ++k) r[k] += __shfl_xor(r[k], off, 64);

    __shared__ float red[4][16];
    const int lane = tid & 63, wave = tid >> 6;
    if (lane == 0) {
#pragma unroll
        for (int k = 0; k < 16; ++k) red[wave][k] = r[k];
    }
    __syncthreads();
    if (tid < 16) {
        const float s = red[0][tid] + red[1][tid] + red[2][tid] + red[3][tid];
        partial[((size_t)chunk * BATCH + b) * HIDDEN + tid] = s;
    }
}

// ---------------------------------------------------------------------------
// K3: out[b][v] = memory[b] . Wo[:,v] + bo[v]  — write-BW bound (51.5 MB).
// grid (ceil(V/256), BATCH/K3_BCHUNK). Block stages 64 memory rows in LDS
// (summing the TCHUNKS partials on the way in); each thread owns one v:
// 16 coalesced Wo loads, 64 coalesced stores.
// ---------------------------------------------------------------------------
__global__ __launch_bounds__(256) void k3_output(
    const float* __restrict__ partial, const float* __restrict__ Wo,
    const float* __restrict__ bo,      float* __restrict__ out)
{
    __shared__ float smem[K3_BCHUNK * 16];
    const int tid = threadIdx.x;
    const int b0 = blockIdx.y * K3_BCHUNK;

#pragma unroll
    for (int i = tid; i < K3_BCHUNK * 16; i += 256) {     // 4 iters
        const int bl = i >> 4, h = i & 15;
        float s = 0.f;
#pragma unroll
        for (int ch = 0; ch < TCHUNKS; ++ch)
            s += partial[((size_t)ch * BATCH + (b0 + bl)) * HIDDEN + h];
        smem[i] = s;
    }
    __syncthreads();

    const int v = blockIdx.x * 256 + tid;
    if (v >= VOCAB) return;

    float w[16];
#pragma unroll
    for (int h = 0; h < 16; ++h) w[h] = Wo[(size_t)h * VOCAB + v];
    const float bias = bo[v];

    float* orow = out + (size_t)b0 * VOCAB + v;
#pragma unroll 4
    for (int bl = 0; bl < K3_BCHUNK; ++bl) {
        float acc = bias;
#pragma unroll
        for (int h = 0; h < 16; ++h)
            acc = fmaf(smem[bl * 16 + h], w[h], acc);     // LDS broadcast reads
        orow[(size_t)bl * VOCAB] = acc;
    }
}

extern "C" void kernel_launch(void* const* d_in, const int* in_sizes, int n_in,
                              void* d_out, int out_size, void* d_ws, size_t ws_size,
                              hipStream_t stream) {
    const int*   seq   = (const int*)  d_in[0];   // [B, T] int32
    const float* embed = (const float*)d_in[1];   // [V, 16]
    const float* Wg    = (const float*)d_in[2];   // [16, 1]
    const float* bg    = (const float*)d_in[3];   // [1]
    const float* Wu    = (const float*)d_in[4];   // [16, 16]
    const float* bu    = (const float*)d_in[5];   // [16]
    const float* Wo    = (const float*)d_in[6];   // [16, V]
    const float* bo    = (const float*)d_in[7];   // [V]
    float* out = (float*)d_out;                   // [B, V] fp32

    float* ctab    = (float*)d_ws;                         // V*16 floats (3.2 MB)
    float* partial = ctab + (size_t)VOCAB * HIDDEN;        // TCHUNKS*B*16 floats

    k1_build_table<<<dim3((VOCAB + 255) / 256), 256, 0, stream>>>(
        embed, Wg, bg, Wu, bu, ctab);
    k2_accum<<<dim3(BATCH, TCHUNKS), 256, 0, stream>>>(seq, ctab, partial);
    k3_output<<<dim3((VOCAB + 255) / 256, BATCH / K3_BCHUNK), 256, 0, stream>>>(
        partial, Wo, bo, out);
}

// Round 2
// 119.979 us; speedup vs baseline: 1.1089x; 1.1089x over previous
//
#include <hip/hip_runtime.h>
#include <cmath>

#define VOCAB   50257
#define HIDDEN  16
#define BATCH   256
#define SEQLEN  8192
#define TCHUNKS 8          // T split for K2 parallelism; partials summed in K3
#define K3_BCHUNK 64       // batch rows per K3 block

// ---------------------------------------------------------------------------
// K1: per-vocab fused table  c[v][k] = sigmoid(Wg.e+bg) * tanh((Wu^T e)[k]+bu[k])
// One thread per vocab row. Wu/Wg/bu staged in LDS (broadcast reads are free).
// ---------------------------------------------------------------------------
__global__ __launch_bounds__(256) void k1_build_table(
    const float* __restrict__ embed, const float* __restrict__ Wg,
    const float* __restrict__ bg,    const float* __restrict__ Wu,
    const float* __restrict__ bu,    float* __restrict__ ctab)
{
    __shared__ float sWu[256], sWg[16], sbu[16];
    const int tid = threadIdx.x;
    sWu[tid] = Wu[tid];
    if (tid < 16) { sWg[tid] = Wg[tid]; sbu[tid] = bu[tid]; }
    __syncthreads();

    const int v = blockIdx.x * 256 + tid;
    if (v >= VOCAB) return;

    const float4* er = (const float4*)(embed + (size_t)v * HIDDEN);
    float4 e0 = er[0], e1 = er[1], e2 = er[2], e3 = er[3];
    float e[16] = {e0.x,e0.y,e0.z,e0.w, e1.x,e1.y,e1.z,e1.w,
                   e2.x,e2.y,e2.z,e2.w, e3.x,e3.y,e3.z,e3.w};

    float z = bg[0];
#pragma unroll
    for (int h = 0; h < 16; ++h) z = fmaf(e[h], sWg[h], z);
    const float g = 1.0f / (1.0f + __expf(-z));

    float o[16];
#pragma unroll
    for (int k = 0; k < 16; ++k) {
        float u = sbu[k];
#pragma unroll
        for (int h = 0; h < 16; ++h) u = fmaf(e[h], sWu[h * 16 + k], u);
        o[k] = g * tanhf(u);
    }

    float4* cr = (float4*)(ctab + (size_t)v * HIDDEN);
    cr[0] = make_float4(o[0],  o[1],  o[2],  o[3]);
    cr[1] = make_float4(o[4],  o[5],  o[6],  o[7]);
    cr[2] = make_float4(o[8],  o[9],  o[10], o[11]);
    cr[3] = make_float4(o[12], o[13], o[14], o[15]);
}

// ---------------------------------------------------------------------------
// K2: memory[b] = sum_t c[seq[b,t]] — gather-sum over L2-resident 3.2 MB table.
// 4-lane-cooperative gather: lanes 4k..4k+3 read the 4 consecutive float4s of
// one row, so each wave instruction touches 16 contiguous 64 B segments
// instead of 64 scattered 16 B ones. grid (BATCH, TCHUNKS), 256 threads.
// ---------------------------------------------------------------------------
__global__ __launch_bounds__(256) void k2_accum(
    const int* __restrict__ seq, const float* __restrict__ ctab,
    float* __restrict__ partial)
{
    const int b = blockIdx.x, chunk = blockIdx.y, tid = threadIdx.x;
    constexpr int TPC = SEQLEN / TCHUNKS;                 // 1024 tokens/chunk
    const int* srow = seq + (size_t)b * SEQLEN + (size_t)chunk * TPC;
    const int sub = tid & 3;                              // which float4 of the row
    const int tok = tid >> 2;                             // token slot 0..63

    float rx = 0.f, ry = 0.f, rz = 0.f, rw = 0.f;
#pragma unroll
    for (int i = 0; i < TPC / 64; ++i) {                  // 16 iters
        const int idx = srow[i * 64 + tok];               // 4 lanes share one addr
        const float4 c = ((const float4*)(ctab + (size_t)idx * HIDDEN))[sub];
        rx += c.x; ry += c.y; rz += c.z; rw += c.w;
    }

    // reduce over lanes with equal sub (bits 2..5 of lane id)
#pragma unroll
    for (int off = 4; off < 64; off <<= 1) {
        rx += __shfl_xor(rx, off, 64);
        ry += __shfl_xor(ry, off, 64);
        rz += __shfl_xor(rz, off, 64);
        rw += __shfl_xor(rw, off, 64);
    }

    __shared__ float red[4][16];
    const int lane = tid & 63, wave = tid >> 6;
    if (lane < 4) {                                       // lane == sub here
        red[wave][lane * 4 + 0] = rx;
        red[wave][lane * 4 + 1] = ry;
        red[wave][lane * 4 + 2] = rz;
        red[wave][lane * 4 + 3] = rw;
    }
    __syncthreads();
    if (tid < 16) {
        partial[((size_t)chunk * BATCH + b) * HIDDEN + tid] =
            red[0][tid] + red[1][tid] + red[2][tid] + red[3][tid];
    }
}

// ---------------------------------------------------------------------------
// K3: out[b][v] = memory[b] . Wo[:,v] + bo[v]  — write-BW bound (51.5 MB).
// grid (ceil(V/256), BATCH/K3_BCHUNK). Block stages 64 memory rows in LDS
// (summing the TCHUNKS partials on the way in); each thread owns one v:
// 16 coalesced Wo loads, 64 coalesced stores.
// ---------------------------------------------------------------------------
__global__ __launch_bounds__(256) void k3_output(
    const float* __restrict__ partial, const float* __restrict__ Wo,
    const float* __restrict__ bo,      float* __restrict__ out)
{
    __shared__ float smem[K3_BCHUNK * 16];
    const int tid = threadIdx.x;
    const int b0 = blockIdx.y * K3_BCHUNK;

#pragma unroll
    for (int i = tid; i < K3_BCHUNK * 16; i += 256) {     // 4 iters
        const int bl = i >> 4, h = i & 15;
        float s = 0.f;
#pragma unroll
        for (int ch = 0; ch < TCHUNKS; ++ch)
            s += partial[((size_t)ch * BATCH + (b0 + bl)) * HIDDEN + h];
        smem[i] = s;
    }
    __syncthreads();

    const int v = blockIdx.x * 256 + tid;
    if (v >= VOCAB) return;

    float w[16];
#pragma unroll
    for (int h = 0; h < 16; ++h) w[h] = Wo[(size_t)h * VOCAB + v];
    const float bias = bo[v];

    float* orow = out + (size_t)b0 * VOCAB + v;
#pragma unroll 4
    for (int bl = 0; bl < K3_BCHUNK; ++bl) {
        float acc = bias;
#pragma unroll
        for (int h = 0; h < 16; ++h)
            acc = fmaf(smem[bl * 16 + h], w[h], acc);     // LDS broadcast reads
        orow[(size_t)bl * VOCAB] = acc;
    }
}

extern "C" void kernel_launch(void* const* d_in, const int* in_sizes, int n_in,
                              void* d_out, int out_size, void* d_ws, size_t ws_size,
                              hipStream_t stream) {
    const int*   seq   = (const int*)  d_in[0];   // [B, T] int32
    const float* embed = (const float*)d_in[1];   // [V, 16]
    const float* Wg    = (const float*)d_in[2];   // [16, 1]
    const float* bg    = (const float*)d_in[3];   // [1]
    const float* Wu    = (const float*)d_in[4];   // [16, 16]
    const float* bu    = (const float*)d_in[5];   // [16]
    const float* Wo    = (const float*)d_in[6];   // [16, V]
    const float* bo    = (const float*)d_in[7];   // [V]
    float* out = (float*)d_out;                   // [B, V] fp32

    float* ctab    = (float*)d_ws;                         // V*16 floats (3.2 MB)
    float* partial = ctab + (size_t)VOCAB * HIDDEN;        // TCHUNKS*B*16 floats

    k1_build_table<<<dim3((VOCAB + 255) / 256), 256, 0, stream>>>(
        embed, Wg, bg, Wu, bu, ctab);
    k2_accum<<<dim3(BATCH, TCHUNKS), 256, 0, stream>>>(seq, ctab, partial);
    k3_output<<<dim3((VOCAB + 255) / 256, BATCH / K3_BCHUNK), 256, 0, stream>>>(
        partial, Wo, bo, out);
}